// Round 3
// baseline (1229.099 us; speedup 1.0000x reference)
//
#include <hip/hip_runtime.h>
#include <hip/hip_cooperative_groups.h>
#include <hip/hip_bf16.h>

namespace cg = cooperative_groups;

#define B_    8
#define O_    4
#define L_    1024
#define E_    1024
#define BETA_ 512
#define NSEG_ 12
#define BO_   32
#define GRID_ 512

// ---- workspace layout (float offsets). Zero-initialized region comes first.
enum : size_t {
  WS_S    = 0,                                   // 32x12x1024 raw segment sums (atomic)
  WS_P1   = WS_S   + (size_t)BO_ * 12 * E_,      // 32x13x1024 raw X@Wp (atomic)
  WS_H1   = WS_P1  + (size_t)BO_ * 13 * E_,      // 32x10x512 raw tE@Wa0 (atomic)
  WS_H2   = WS_H1  + (size_t)BO_ * 10 * BETA_,   // 32x512 raw IAB@Wa0 (atomic)
  WS_H3   = WS_H2  + (size_t)BO_ * BETA_,        // 32x10x512 raw RN@Wa0 (atomic)
  WS_HF   = WS_H3  + (size_t)BO_ * 10 * BETA_,   // 32x512 raw CAT@Wl0 (atomic)
  WS_ZEND = WS_HF  + (size_t)BO_ * BETA_,        // end of zeroed region
  WS_X    = WS_ZEND,                             // 32x13x1024 segment means
  WS_T1B  = WS_X   + (size_t)BO_ * 13 * E_,      // 32x10x512 biased pool-1 logits
  WS_IAB  = WS_T1B + (size_t)BO_ * 10 * BETA_,   // 32x1024 ia|ib
  WS_RN   = WS_IAB + (size_t)BO_ * 2 * BETA_,    // 32x10x1024 1/na|1/nb
  WS_CAT  = WS_RN  + (size_t)BO_ * 10 * E_,      // 32x4096 cat
  WS_END  = WS_CAT + (size_t)BO_ * 8 * BETA_,
};

__device__ __forceinline__ float relu_(float v) { return v > 0.f ? v : 0.f; }
__device__ __forceinline__ float vget(const float4& v, int kk) {
    return (kk == 0) ? v.x : (kk == 1) ? v.y : (kk == 2) ? v.z : v.w;
}

// split-K / split-bo / split-N GEMM task with fused x-load transform.
// OUT[(bo*M+m)*N + c] += sum_k xform(X[bo*XBO + m*K + k]) * W[k*N + c]
// XF: 0 = identity, 1 = 1+relu(v+bias[k]), 2 = relu(v+bias[k])
template<int M, int K, int N, int KC, int BOG, int XF, int XBO>
__device__ void gemm_task(int task, const float* __restrict__ Xb,
                          const float* __restrict__ xbias,
                          const float* __restrict__ W,
                          float* __restrict__ OUT, float* xs, int tid) {
    constexpr int NCH = N / 256;
    constexpr int NBOG = BO_ / BOG;
    const int nidx = task % NCH;
    const int rest = task / NCH;
    const int bidx = rest % NBOG;
    const int kidx = rest / NBOG;
    const int k0 = kidx * KC;
    const int bo0 = bidx * BOG;
    const int c = nidx * 256 + tid;
    for (int i = tid; i < BOG * M * KC; i += 256) {
        const int kk = i % KC;
        const int rm = i / KC;
        const int m = rm % M;
        const int b = rm / M;
        float v = Xb[(size_t)(bo0 + b) * XBO + (size_t)m * K + k0 + kk];
        if constexpr (XF >= 1) {
            v += xbias[k0 + kk];
            v = relu_(v);
            if constexpr (XF == 1) v += 1.f;
        }
        xs[i] = v;
    }
    __syncthreads();
    float acc[BOG][M];
#pragma unroll
    for (int b = 0; b < BOG; ++b)
#pragma unroll
        for (int m = 0; m < M; ++m) acc[b][m] = 0.f;
    const float* __restrict__ wp = W + (size_t)k0 * N + c;
    for (int k4 = 0; k4 < KC / 4; ++k4) {
        const float w0 = wp[(size_t)(4 * k4 + 0) * N];
        const float w1 = wp[(size_t)(4 * k4 + 1) * N];
        const float w2 = wp[(size_t)(4 * k4 + 2) * N];
        const float w3 = wp[(size_t)(4 * k4 + 3) * N];
#pragma unroll
        for (int b = 0; b < BOG; ++b) {
#pragma unroll
            for (int m = 0; m < M; ++m) {
                const float4 xv = *reinterpret_cast<const float4*>(&xs[(b * M + m) * KC + 4 * k4]);
                float a = acc[b][m];
                a = fmaf(xv.x, w0, a);
                a = fmaf(xv.y, w1, a);
                a = fmaf(xv.z, w2, a);
                a = fmaf(xv.w, w3, a);
                acc[b][m] = a;
            }
        }
    }
#pragma unroll
    for (int b = 0; b < BOG; ++b) {
        float* op = OUT + (size_t)(bo0 + b) * M * N + c;
#pragma unroll
        for (int m = 0; m < M; ++m) atomicAdd(op + (size_t)m * N, acc[b][m]);
    }
    __syncthreads();
}

__global__ void __launch_bounds__(256, 2) mega(
    const float* __restrict__ hidden, const int* __restrict__ idx,
    const float* __restrict__ Wp, const float* __restrict__ bp,
    const float* __restrict__ Wa0, const float* __restrict__ ba0,
    const float* __restrict__ Wa, const float* __restrict__ ba,
    const float* __restrict__ Wl0, const float* __restrict__ bl0,
    const float* __restrict__ Wl, const float* __restrict__ bl,
    float* __restrict__ ws, float* __restrict__ out) {
    cg::grid_group gg = cg::this_grid();
    const int gid = blockIdx.x;
    const int tid = threadIdx.x;
    __shared__ __align__(16) float smem[10 * BETA_];  // 20 KB, reused by all phases

    float* S   = ws + WS_S;
    float* P1  = ws + WS_P1;
    float* H1  = ws + WS_H1;
    float* H2  = ws + WS_H2;
    float* H3  = ws + WS_H3;
    float* HF  = ws + WS_HF;
    float* X   = ws + WS_X;
    float* T1B = ws + WS_T1B;
    float* IAB = ws + WS_IAB;
    float* RN  = ws + WS_RN;
    float* CAT = ws + WS_CAT;

    // ---- P0: zero the atomic accumulators -------------------------------------------
    {
        float4* z4 = reinterpret_cast<float4*>(ws);
        const size_t n4 = WS_ZEND / 4;
        const float4 z = make_float4(0.f, 0.f, 0.f, 0.f);
        for (size_t i = (size_t)gid * 256 + tid; i < n4; i += (size_t)GRID_ * 256) z4[i] = z;
    }
    __threadfence();
    gg.sync();

    // ---- P1: segment sums over L (streams the 128 MB hidden tensor) ----------------
    {
        const int task = gid;  // 512 tasks = 32 bo x 16 chunks
        const int bo = task >> 4;
        const int chunk = task & 15;
        const int b = bo >> 2;
        int cuts[13];
        cuts[0] = 1;
#pragma unroll
        for (int i = 0; i < 12; ++i) cuts[i + 1] = idx[b * NSEG_ + i];
        const int l0 = chunk * 64;
        const int l1 = l0 + 64;
        int lo = l0 < 1 ? 1 : l0;
        const int hi = l1 < cuts[12] ? l1 : cuts[12];
        if (lo < hi) {
            const int e4 = tid << 2;
            const float* base = hidden + (size_t)bo * (L_ * E_) + e4;
            int j = 0;
            while (j < 11 && cuts[j + 1] <= lo) ++j;
            int l = lo;
            while (l < hi) {
                const int e2 = (j < 11 && cuts[j + 1] < hi) ? cuts[j + 1] : hi;
                float sx = 0.f, sy = 0.f, sz = 0.f, sw = 0.f;
                for (; l < e2; ++l) {
                    const float4 v = *reinterpret_cast<const float4*>(base + (size_t)l * E_);
                    sx += v.x; sy += v.y; sz += v.z; sw += v.w;
                }
                float* sp = S + ((size_t)bo * 12 + j) * E_ + e4;
                atomicAdd(sp + 0, sx);
                atomicAdd(sp + 1, sy);
                atomicAdd(sp + 2, sz);
                atomicAdd(sp + 3, sw);
                ++j;
            }
        }
    }
    __threadfence();
    gg.sync();

    // ---- P2: segment means (rows 0..9 ctx, 10 q, 11 o, 12 allc) ---------------------
    if (gid < BO_) {
        const int bo = gid;
        const int b = bo >> 2;
        int cuts[13];
        cuts[0] = 1;
#pragma unroll
        for (int i = 0; i < 12; ++i) cuts[i + 1] = idx[b * NSEG_ + i];
        const int e4 = tid << 2;
        const float4* Sp = reinterpret_cast<const float4*>(S + (size_t)bo * 12 * E_ + e4);
        float4* Xp = reinterpret_cast<float4*>(X + (size_t)bo * 13 * E_ + e4);
        float ax = 0.f, ay = 0.f, az = 0.f, aw = 0.f;
#pragma unroll
        for (int r = 0; r < 12; ++r) {
            const float4 s = Sp[r * (E_ / 4)];
            const float inv = 1.0f / (float)(cuts[r + 1] - cuts[r]);
            float4 m;
            m.x = s.x * inv; m.y = s.y * inv; m.z = s.z * inv; m.w = s.w * inv;
            Xp[r * (E_ / 4)] = m;
            if (r < 10) { ax += s.x; ay += s.y; az += s.z; aw += s.w; }
        }
        const float inva = 1.0f / (float)(cuts[10] - 1);
        float4 m;
        m.x = ax * inva; m.y = ay * inva; m.z = az * inva; m.w = aw * inva;
        Xp[12 * (E_ / 4)] = m;
    }
    __threadfence();
    gg.sync();

    // ---- P3 (G1): P1 += X @ Wp   M=13 K=1024 N=1024, 8x16x4 = 512 tasks -------------
    for (int t = gid; t < 512; t += GRID_)
        gemm_task<13, 1024, 1024, 128, 2, 0, 13 * 1024>(t, X, nullptr, Wp, P1, smem, tid);
    __threadfence();
    gg.sync();

    // ---- P4 (G2): H1 += (1+relu(P1+bp)) @ Wa0   M=10 K=1024 N=512, 16x16x2=512 ------
    for (int t = gid; t < 512; t += GRID_)
        gemm_task<10, 1024, 512, 64, 2, 1, 13 * 1024>(t, P1, bp, Wa0, H1, smem, tid);
    __threadfence();
    gg.sync();

    // ---- P5 (F3): T1B = relu(H1+ba0)@Wa + ba ; softmax over j ; IAB -----------------
    if (gid < 64) {
        const int bo = gid >> 1;
        const int c = ((gid & 1) << 8) + tid;  // 0..511
        for (int i4 = tid; i4 < 1280; i4 += 256) {
            const int j = i4 >> 7;
            const int k4 = i4 & 127;
            const float4 v = *reinterpret_cast<const float4*>(H1 + ((size_t)bo * 10 + j) * BETA_ + 4 * k4);
            const float4 b4 = *reinterpret_cast<const float4*>(ba0 + 4 * k4);
            float4 r;
            r.x = relu_(v.x + b4.x); r.y = relu_(v.y + b4.y);
            r.z = relu_(v.z + b4.z); r.w = relu_(v.w + b4.w);
            *reinterpret_cast<float4*>(&smem[j * BETA_ + 4 * k4]) = r;
        }
        __syncthreads();
        float acc[10];
#pragma unroll
        for (int j = 0; j < 10; ++j) acc[j] = 0.f;
        const float* wp = Wa + c;
        for (int k4 = 0; k4 < 128; ++k4) {
            const float w0 = wp[(4 * k4 + 0) * BETA_];
            const float w1 = wp[(4 * k4 + 1) * BETA_];
            const float w2 = wp[(4 * k4 + 2) * BETA_];
            const float w3 = wp[(4 * k4 + 3) * BETA_];
#pragma unroll
            for (int j = 0; j < 10; ++j) {
                const float4 hv = *reinterpret_cast<const float4*>(&smem[j * BETA_ + 4 * k4]);
                float a = acc[j];
                a = fmaf(hv.x, w0, a); a = fmaf(hv.y, w1, a);
                a = fmaf(hv.z, w2, a); a = fmaf(hv.w, w3, a);
                acc[j] = a;
            }
        }
        const float bac = ba[c];
        float t[10];
#pragma unroll
        for (int j = 0; j < 10; ++j) {
            t[j] = acc[j] + bac;
            T1B[((size_t)bo * 10 + j) * BETA_ + c] = t[j];
        }
        float m = t[0];
#pragma unroll
        for (int j = 1; j < 10; ++j) m = fmaxf(m, t[j]);
        float p[10], sw = 0.f;
#pragma unroll
        for (int j = 0; j < 10; ++j) { p[j] = expf(t[j] - m); sw += p[j]; }
        const float inv = 1.0f / sw;
        const float bpa = bp[c], bpb = bp[BETA_ + c];
        const float* Pp = P1 + (size_t)bo * 13 * E_;
        float ia = 0.f, ib = 0.f;
#pragma unroll
        for (int j = 0; j < 10; ++j) {
            const float pj = p[j] * inv;
            const float ea = 1.f + relu_(Pp[(size_t)j * E_ + c] + bpa);
            const float eb = 1.f + relu_(Pp[(size_t)j * E_ + BETA_ + c] + bpb);
            ia = fmaf(pj, ea, ia);
            ib = fmaf(pj, eb, ib);
        }
        IAB[(size_t)bo * 1024 + c] = ia;
        IAB[(size_t)bo * 1024 + BETA_ + c] = ib;
        __syncthreads();
    }
    __threadfence();
    gg.sync();

    // ---- P6 (G4): H2 += IAB @ Wa0   M=1 K=1024 N=512, 8x4x2 = 64 tasks --------------
    for (int t = gid; t < 64; t += GRID_)
        gemm_task<1, 1024, 512, 128, 8, 0, 1024>(t, IAB, nullptr, Wa0, H2, smem, tid);
    __threadfence();
    gg.sync();

    // ---- P7 (F5): tI = relu(H2+ba0)@Wa + ba ; 2-way softmax vs T1B -> RN ------------
    if (gid < 64) {
        const int bo = gid >> 1;
        const int c = ((gid & 1) << 8) + tid;
        for (int i4 = tid; i4 < 128; i4 += 256) {
            const float4 v = *reinterpret_cast<const float4*>(H2 + (size_t)bo * BETA_ + 4 * i4);
            const float4 b4 = *reinterpret_cast<const float4*>(ba0 + 4 * i4);
            float4 r;
            r.x = relu_(v.x + b4.x); r.y = relu_(v.y + b4.y);
            r.z = relu_(v.z + b4.z); r.w = relu_(v.w + b4.w);
            *reinterpret_cast<float4*>(&smem[4 * i4]) = r;
        }
        __syncthreads();
        float tI = 0.f;
        const float* wp = Wa + c;
        for (int k4 = 0; k4 < 128; ++k4) {
            const float4 hv = *reinterpret_cast<const float4*>(&smem[4 * k4]);
            tI = fmaf(hv.x, wp[(4 * k4 + 0) * BETA_], tI);
            tI = fmaf(hv.y, wp[(4 * k4 + 1) * BETA_], tI);
            tI = fmaf(hv.z, wp[(4 * k4 + 2) * BETA_], tI);
            tI = fmaf(hv.w, wp[(4 * k4 + 3) * BETA_], tI);
        }
        tI += ba[c];
        const float ia = IAB[(size_t)bo * 1024 + c];
        const float ib = IAB[(size_t)bo * 1024 + BETA_ + c];
        const float bpa = bp[c], bpb = bp[BETA_ + c];
        const float* Pp = P1 + (size_t)bo * 13 * E_;
#pragma unroll
        for (int j = 0; j < 10; ++j) {
            const float tj = T1B[((size_t)bo * 10 + j) * BETA_ + c];
            const float m = fmaxf(tj, tI);
            const float e0 = expf(tj - m);
            const float e1 = expf(tI - m);
            const float inv = 1.0f / (e0 + e1);
            const float ea = 1.f + relu_(Pp[(size_t)j * E_ + c] + bpa);
            const float eb = 1.f + relu_(Pp[(size_t)j * E_ + BETA_ + c] + bpb);
            const float na = (e0 * ea + e1 * ia) * inv;
            const float nb = (e0 * eb + e1 * ib) * inv;
            RN[((size_t)bo * 10 + j) * E_ + c] = 1.0f / na;
            RN[((size_t)bo * 10 + j) * E_ + BETA_ + c] = 1.0f / nb;
        }
        __syncthreads();
    }
    __threadfence();
    gg.sync();

    // ---- P8 (G6): H3 += RN @ Wa0   M=10 K=1024 N=512, 16x16x2 = 512 tasks -----------
    for (int t = gid; t < 512; t += GRID_)
        gemm_task<10, 1024, 512, 64, 2, 0, 10 * 1024>(t, RN, nullptr, Wa0, H3, smem, tid);
    __threadfence();
    gg.sync();

    // ---- P9 (F7): t3 = relu(H3+ba0)@Wa + ba ; softmax over j ; build CAT ------------
    if (gid < 64) {
        const int bo = gid >> 1;
        const int c = ((gid & 1) << 8) + tid;
        for (int i4 = tid; i4 < 1280; i4 += 256) {
            const int j = i4 >> 7;
            const int k4 = i4 & 127;
            const float4 v = *reinterpret_cast<const float4*>(H3 + ((size_t)bo * 10 + j) * BETA_ + 4 * k4);
            const float4 b4 = *reinterpret_cast<const float4*>(ba0 + 4 * k4);
            float4 r;
            r.x = relu_(v.x + b4.x); r.y = relu_(v.y + b4.y);
            r.z = relu_(v.z + b4.z); r.w = relu_(v.w + b4.w);
            *reinterpret_cast<float4*>(&smem[j * BETA_ + 4 * k4]) = r;
        }
        __syncthreads();
        float acc[10];
#pragma unroll
        for (int j = 0; j < 10; ++j) acc[j] = 0.f;
        const float* wp = Wa + c;
        for (int k4 = 0; k4 < 128; ++k4) {
            const float w0 = wp[(4 * k4 + 0) * BETA_];
            const float w1 = wp[(4 * k4 + 1) * BETA_];
            const float w2 = wp[(4 * k4 + 2) * BETA_];
            const float w3 = wp[(4 * k4 + 3) * BETA_];
#pragma unroll
            for (int j = 0; j < 10; ++j) {
                const float4 hv = *reinterpret_cast<const float4*>(&smem[j * BETA_ + 4 * k4]);
                float a = acc[j];
                a = fmaf(hv.x, w0, a); a = fmaf(hv.y, w1, a);
                a = fmaf(hv.z, w2, a); a = fmaf(hv.w, w3, a);
                acc[j] = a;
            }
        }
        const float bac = ba[c];
        float t[10];
        float m = -1e30f;
#pragma unroll
        for (int j = 0; j < 10; ++j) { t[j] = acc[j] + bac; m = fmaxf(m, t[j]); }
        float p[10], sw = 0.f;
#pragma unroll
        for (int j = 0; j < 10; ++j) { p[j] = expf(t[j] - m); sw += p[j]; }
        const float inv = 1.0f / sw;
        float uap = 0.f, ubp = 0.f;
#pragma unroll
        for (int j = 0; j < 10; ++j) {
            const float pj = p[j] * inv;
            uap = fmaf(pj, RN[((size_t)bo * 10 + j) * E_ + c], uap);
            ubp = fmaf(pj, RN[((size_t)bo * 10 + j) * E_ + BETA_ + c], ubp);
        }
        const float bpa = bp[c], bpb = bp[BETA_ + c];
        const float* Pp = P1 + (size_t)bo * 13 * E_;
        float* catp = CAT + (size_t)bo * 4096;
        catp[c] = 1.0f / uap;
        catp[BETA_ + c] = 1.0f / ubp;
        catp[1024 + c]         = 1.f + relu_(Pp[12 * E_ + c] + bpa);
        catp[1024 + BETA_ + c] = 1.f + relu_(Pp[12 * E_ + BETA_ + c] + bpb);
        catp[2048 + c]         = 1.f + relu_(Pp[11 * E_ + c] + bpa);
        catp[2048 + BETA_ + c] = 1.f + relu_(Pp[11 * E_ + BETA_ + c] + bpb);
        catp[3072 + c]         = 1.f + relu_(Pp[10 * E_ + c] + bpa);
        catp[3072 + BETA_ + c] = 1.f + relu_(Pp[10 * E_ + BETA_ + c] + bpb);
        __syncthreads();
    }
    __threadfence();
    gg.sync();

    // ---- P10 (G8): HF += CAT @ Wl0   M=1 K=4096 N=512, 32x4x2 = 256 tasks -----------
    for (int t = gid; t < 256; t += GRID_)
        gemm_task<1, 4096, 512, 128, 8, 0, 4096>(t, CAT, nullptr, Wl0, HF, smem, tid);
    __threadfence();
    gg.sync();

    // ---- P11: out[bo] = relu(HF+bl0) . Wl + bl --------------------------------------
    if (gid < BO_) {
        const int bo = gid;
        const float v1 = relu_(HF[(size_t)bo * BETA_ + tid] + bl0[tid]) * Wl[tid];
        const float v2 = relu_(HF[(size_t)bo * BETA_ + 256 + tid] + bl0[256 + tid]) * Wl[256 + tid];
        float partial = v1 + v2;
#pragma unroll
        for (int off = 32; off > 0; off >>= 1) partial += __shfl_down(partial, off, 64);
        if ((tid & 63) == 0) smem[tid >> 6] = partial;
        __syncthreads();
        if (tid == 0) out[bo] = smem[0] + smem[1] + smem[2] + smem[3] + bl[0];
    }
}

extern "C" void kernel_launch(void* const* d_in, const int* in_sizes, int n_in,
                              void* d_out, int out_size, void* d_ws, size_t ws_size,
                              hipStream_t stream) {
    const float* hidden = (const float*)d_in[0];
    const int* idx = (const int*)d_in[1];
    const float* Wp  = (const float*)d_in[2];
    const float* bp  = (const float*)d_in[3];
    const float* Wa0 = (const float*)d_in[4];
    const float* ba0 = (const float*)d_in[5];
    const float* Wa  = (const float*)d_in[6];
    const float* ba  = (const float*)d_in[7];
    const float* Wl0 = (const float*)d_in[8];
    const float* bl0 = (const float*)d_in[9];
    const float* Wl  = (const float*)d_in[10];
    const float* bl  = (const float*)d_in[11];
    float* ws = (float*)d_ws;
    float* out = (float*)d_out;

    void* kargs[] = {
        (void*)&hidden, (void*)&idx, (void*)&Wp, (void*)&bp,
        (void*)&Wa0, (void*)&ba0, (void*)&Wa, (void*)&ba,
        (void*)&Wl0, (void*)&bl0, (void*)&Wl, (void*)&bl,
        (void*)&ws, (void*)&out,
    };
    hipLaunchCooperativeKernel((const void*)mega, dim3(GRID_), dim3(256), kargs, 0, stream);
}

// Round 4
// 189.443 us; speedup vs baseline: 6.4880x; 6.4880x over previous
//
#include <hip/hip_runtime.h>
#include <hip/hip_bf16.h>

#define B_    8
#define O_    4
#define L_    1024
#define E_    1024
#define BETA_ 512
#define NSEG_ 12
#define BO_   32

// ---- workspace layout (float offsets). [0 .. WS_ZEND) is memset to 0 each call.
enum : size_t {
  WS_S    = 0,                                   // 32x12x1024 raw segment sums (atomic)
  WS_P1   = WS_S   + (size_t)BO_ * 12 * E_,      // 32x13x1024 raw X@Wp (atomic)
  WS_H1   = WS_P1  + (size_t)BO_ * 13 * E_,      // 32x10x512 raw tE@Wa0 (atomic)
  WS_T1   = WS_H1  + (size_t)BO_ * 10 * BETA_,   // 32x10x512 raw h@Wa (atomic)
  WS_H2   = WS_T1  + (size_t)BO_ * 10 * BETA_,   // 32x512 raw IAB@Wa0 (atomic)
  WS_T2   = WS_H2  + (size_t)BO_ * BETA_,        // 32x512 raw hI@Wa (atomic)
  WS_H3   = WS_T2  + (size_t)BO_ * BETA_,        // 32x10x512 raw RN@Wa0 (atomic)
  WS_T3   = WS_H3  + (size_t)BO_ * 10 * BETA_,   // 32x10x512 raw h3@Wa (atomic)
  WS_HF   = WS_T3  + (size_t)BO_ * 10 * BETA_,   // 32x512 raw CAT@Wl0 (atomic)
  WS_ZEND = WS_HF  + (size_t)BO_ * BETA_,        // end of zeroed region
  WS_IAB  = WS_ZEND,                             // 32x1024 ia|ib (plain writes)
  WS_RN   = WS_IAB + (size_t)BO_ * 2 * BETA_,    // 32x10x1024 1/na|1/nb (plain writes)
  WS_END  = WS_RN  + (size_t)BO_ * 10 * E_,
};

__device__ __forceinline__ float relu_(float v) { return v > 0.f ? v : 0.f; }

// ---------------- K1: segment sums over L (the only big-memory kernel) ----------------
__global__ void k1_segsum(const float* __restrict__ hidden, const int* __restrict__ idx,
                          float* __restrict__ S) {
    const int bo = blockIdx.y;
    const int b = bo >> 2;
    int cuts[13];
    cuts[0] = 1;
#pragma unroll
    for (int i = 0; i < 12; ++i) cuts[i + 1] = idx[b * NSEG_ + i];
    const int rows = L_ / 64;
    const int l0 = blockIdx.x * rows;
    const int l1 = l0 + rows;
    int lo = l0 < 1 ? 1 : l0;
    const int hi = l1 < cuts[12] ? l1 : cuts[12];
    if (lo >= hi) return;
    const int e4 = threadIdx.x << 2;
    const float* base = hidden + (size_t)bo * (L_ * E_) + e4;
    int j = 0;
    while (j < 11 && cuts[j + 1] <= lo) ++j;
    int l = lo;
    while (l < hi) {
        const int e2 = (j < 11 && cuts[j + 1] < hi) ? cuts[j + 1] : hi;
        float sx = 0.f, sy = 0.f, sz = 0.f, sw = 0.f;
        for (; l < e2; ++l) {
            const float4 v = *reinterpret_cast<const float4*>(base + (size_t)l * E_);
            sx += v.x; sy += v.y; sz += v.z; sw += v.w;
        }
        float* sp = S + ((size_t)bo * 12 + j) * E_ + e4;
        atomicAdd(sp + 0, sx);
        atomicAdd(sp + 1, sy);
        atomicAdd(sp + 2, sz);
        atomicAdd(sp + 3, sw);
        ++j;
    }
}

// ---------------- split-K / split-bo / split-N GEMM with fused x-loader ---------------
// OUT[(bo*M+m)*N + c] += sum_k xval(bo,m,k) * W[k*N + c]
// XF: 0 identity        xval = Xb[bo*XBO + m*K + k]
//     1 1+relu(v+xb[k]) (P1 -> tE)
//     2 relu(v+xb[k])   (H -> h)
//     3 seg-means from S (needs idxp; m=12 = allc)
//     4 IAB on-the-fly   (A0=T1,A1=P1,A2=ba,A3=bp; SIDE=IAB)
//     5 RN  on-the-fly   (A0=T1,A1=T2,A2=IAB,A3=P1,A4=ba,A5=bp; SIDE=RN)
//     6 CAT on-the-fly   (A0=T3,A1=RN,A2=P1,A3=ba,A4=bp)
template<int M, int K, int N, int KC, int BOG, int XF, int XBO>
__global__ __launch_bounds__(256) void gemm_sk(
    const float* __restrict__ Xb, const float* __restrict__ xbias,
    const float* __restrict__ W, float* __restrict__ OUT,
    const float* __restrict__ A0, const float* __restrict__ A1,
    const float* __restrict__ A2, const float* __restrict__ A3,
    const float* __restrict__ A4, const float* __restrict__ A5,
    float* __restrict__ SIDE, const int* __restrict__ idxp) {
    const int k0  = blockIdx.x * KC;
    const int bo0 = blockIdx.y * BOG;
    const int c   = blockIdx.z * 256 + threadIdx.x;
    const int tid = threadIdx.x;
    __shared__ __align__(16) float xs[BOG * M * KC];

    float invc[12], invall;
    if constexpr (XF == 3) {
        int cuts[13];
        cuts[0] = 1;
        const int b0 = bo0 >> 2;  // BOG=2, bo0 even -> same b for both bos
#pragma unroll
        for (int i = 0; i < 12; ++i) cuts[i + 1] = idxp[b0 * NSEG_ + i];
#pragma unroll
        for (int m = 0; m < 12; ++m) invc[m] = 1.0f / (float)(cuts[m + 1] - cuts[m]);
        invall = 1.0f / (float)(cuts[10] - 1);
    }

    for (int i = tid; i < BOG * M * KC; i += 256) {
        const int kk = i % KC;
        const int rm = i / KC;
        const int m  = rm % M;
        const int bb = rm / M;
        const int bo = bo0 + bb;
        const int k  = k0 + kk;
        float v;
        if constexpr (XF == 0) {
            v = Xb[(size_t)bo * XBO + (size_t)m * K + k];
        } else if constexpr (XF == 1 || XF == 2) {
            v = Xb[(size_t)bo * XBO + (size_t)m * K + k] + xbias[k];
            v = relu_(v);
            if constexpr (XF == 1) v += 1.f;
        } else if constexpr (XF == 3) {
            if (m < 12) {
                v = Xb[((size_t)bo * 12 + m) * E_ + k] * invc[m];
            } else {
                float s = 0.f;
#pragma unroll
                for (int r = 0; r < 10; ++r) s += Xb[((size_t)bo * 12 + r) * E_ + k];
                v = s * invall;
            }
        } else if constexpr (XF == 4) {
            // IAB: k in [0,1024): half=k>>9 selects a vs b, col=k&511
            const int col = k & 511, half = k >> 9;
            const float bac = A2[col];
            float t[10], mx = -1e30f;
#pragma unroll
            for (int j = 0; j < 10; ++j) {
                t[j] = A0[((size_t)bo * 10 + j) * BETA_ + col] + bac;
                mx = fmaxf(mx, t[j]);
            }
            float p[10], sw = 0.f;
#pragma unroll
            for (int j = 0; j < 10; ++j) { p[j] = expf(t[j] - mx); sw += p[j]; }
            const float bpc = A3[half * BETA_ + col];
            float acc = 0.f;
#pragma unroll
            for (int j = 0; j < 10; ++j) {
                const float e = 1.f + relu_(A1[(size_t)bo * 13 * E_ + (size_t)j * E_ + half * BETA_ + col] + bpc);
                acc = fmaf(p[j], e, acc);
            }
            v = acc / sw;
            SIDE[(size_t)bo * 1024 + k] = v;
        } else if constexpr (XF == 5) {
            // RN: j = m, k in [0,1024)
            const int col = k & 511, half = k >> 9;
            const int j = m;
            const float bac = A4[col];
            const float tj = A0[((size_t)bo * 10 + j) * BETA_ + col] + bac;
            const float tI = A1[(size_t)bo * BETA_ + col] + bac;
            const float mx = fmaxf(tj, tI);
            const float e0 = expf(tj - mx);
            const float e1 = expf(tI - mx);
            const float iv = A2[(size_t)bo * 1024 + half * BETA_ + col];
            const float ea = 1.f + relu_(A3[(size_t)bo * 13 * E_ + (size_t)j * E_ + half * BETA_ + col] + A5[half * BETA_ + col]);
            v = (e0 + e1) / (e0 * ea + e1 * iv);  // = 1/na (or 1/nb)
            SIDE[((size_t)bo * 10 + j) * 1024 + k] = v;
        } else {  // XF == 6, CAT: k in [0,4096)
            if (k < 1024) {
                const int col = k & 511, half = k >> 9;
                const float bac = A3[col];
                float t[10], mx = -1e30f;
#pragma unroll
                for (int j = 0; j < 10; ++j) {
                    t[j] = A0[((size_t)bo * 10 + j) * BETA_ + col] + bac;
                    mx = fmaxf(mx, t[j]);
                }
                float sw = 0.f, acc = 0.f;
#pragma unroll
                for (int j = 0; j < 10; ++j) {
                    const float p = expf(t[j] - mx);
                    sw += p;
                    acc = fmaf(p, A1[((size_t)bo * 10 + j) * 1024 + half * BETA_ + col], acc);
                }
                v = sw / acc;  // 1/(sum p_j rn_j / sum p)
            } else {
                const int region = k >> 10;  // 1,2,3
                const int row = (region == 1) ? 12 : (region == 2) ? 11 : 10;
                const int col = k & 1023;
                v = 1.f + relu_(A2[(size_t)bo * 13 * E_ + (size_t)row * E_ + col] + A4[col]);
            }
        }
        xs[i] = v;
    }
    __syncthreads();

    float acc[BOG][M];
#pragma unroll
    for (int b = 0; b < BOG; ++b)
#pragma unroll
        for (int m = 0; m < M; ++m) acc[b][m] = 0.f;
    const float* __restrict__ wp = W + (size_t)k0 * N + c;
    for (int k4 = 0; k4 < KC / 4; ++k4) {
        const float w0 = wp[(size_t)(4 * k4 + 0) * N];
        const float w1 = wp[(size_t)(4 * k4 + 1) * N];
        const float w2 = wp[(size_t)(4 * k4 + 2) * N];
        const float w3 = wp[(size_t)(4 * k4 + 3) * N];
#pragma unroll
        for (int b = 0; b < BOG; ++b) {
#pragma unroll
            for (int m = 0; m < M; ++m) {
                const float4 xv = *reinterpret_cast<const float4*>(&xs[(b * M + m) * KC + 4 * k4]);
                float a = acc[b][m];
                a = fmaf(xv.x, w0, a);
                a = fmaf(xv.y, w1, a);
                a = fmaf(xv.z, w2, a);
                a = fmaf(xv.w, w3, a);
                acc[b][m] = a;
            }
        }
    }
#pragma unroll
    for (int b = 0; b < BOG; ++b) {
        float* op = OUT + (size_t)(bo0 + b) * M * N + c;
#pragma unroll
        for (int m = 0; m < M; ++m) atomicAdd(op + (size_t)m * N, acc[b][m]);
    }
}

// ---------------- final: out[bo] = relu(HF+bl0) . Wl + bl -----------------------------
__global__ void __launch_bounds__(512) k_final(
    const float* __restrict__ HF, const float* __restrict__ bl0,
    const float* __restrict__ Wl, const float* __restrict__ bl,
    float* __restrict__ out) {
    const int bo = blockIdx.x;
    const int c = threadIdx.x;
    const float v1 = relu_(HF[(size_t)bo * BETA_ + c] + bl0[c]) * Wl[c];
    const float v2 = relu_(HF[(size_t)bo * BETA_ + 256 + c] + bl0[256 + c]) * Wl[256 + c];
    float partial = v1 + v2;
#pragma unroll
    for (int off = 32; off > 0; off >>= 1) partial += __shfl_down(partial, off, 64);
    __shared__ float red[8];
    if ((c & 63) == 0) red[c >> 6] = partial;
    __syncthreads();
    if (c == 0) out[bo] = red[0] + red[1] + red[2] + red[3] + bl[0];
}

extern "C" void kernel_launch(void* const* d_in, const int* in_sizes, int n_in,
                              void* d_out, int out_size, void* d_ws, size_t ws_size,
                              hipStream_t stream) {
    const float* hidden = (const float*)d_in[0];
    const int* idx = (const int*)d_in[1];
    const float* Wp  = (const float*)d_in[2];
    const float* bp  = (const float*)d_in[3];
    const float* Wa0 = (const float*)d_in[4];
    const float* ba0 = (const float*)d_in[5];
    const float* Wa  = (const float*)d_in[6];
    const float* ba  = (const float*)d_in[7];
    const float* Wl0 = (const float*)d_in[8];
    const float* bl0 = (const float*)d_in[9];
    const float* Wl  = (const float*)d_in[10];
    const float* bl  = (const float*)d_in[11];
    float* ws = (float*)d_ws;
    float* S   = ws + WS_S;
    float* P1  = ws + WS_P1;
    float* H1  = ws + WS_H1;
    float* T1  = ws + WS_T1;
    float* H2  = ws + WS_H2;
    float* T2  = ws + WS_T2;
    float* H3  = ws + WS_H3;
    float* T3  = ws + WS_T3;
    float* HF  = ws + WS_HF;
    float* IAB = ws + WS_IAB;
    float* RN  = ws + WS_RN;
    const float* NUL = nullptr;

    hipMemsetAsync(S, 0, (size_t)WS_ZEND * sizeof(float), stream);
    k1_segsum<<<dim3(64, BO_), 256, 0, stream>>>(hidden, idx, S);
    // G1: P1 += means(S) @ Wp   (M=13, K=1024, N=1024) — means fused into loader
    gemm_sk<13, 1024, 1024, 128, 2, 3, 0>
        <<<dim3(8, 16, 4), 256, 0, stream>>>(S, NUL, Wp, P1, NUL, NUL, NUL, NUL, NUL, NUL, nullptr, idx);
    // G2: H1 += (1+relu(P1+bp)) @ Wa0
    gemm_sk<10, 1024, 512, 64, 2, 1, 13 * 1024>
        <<<dim3(16, 16, 2), 256, 0, stream>>>(P1, bp, Wa0, H1, NUL, NUL, NUL, NUL, NUL, NUL, nullptr, nullptr);
    // G3: T1 += relu(H1+ba0) @ Wa
    gemm_sk<10, 512, 512, 64, 2, 2, 10 * 512>
        <<<dim3(8, 16, 2), 256, 0, stream>>>(H1, ba0, Wa, T1, NUL, NUL, NUL, NUL, NUL, NUL, nullptr, nullptr);
    // G4: H2 += IAB @ Wa0 — pool-1 softmax fused into loader, side-writes IAB
    gemm_sk<1, 1024, 512, 128, 8, 4, 0>
        <<<dim3(8, 4, 2), 256, 0, stream>>>(NUL, NUL, Wa0, H2, T1, P1, ba, bp, NUL, NUL, IAB, nullptr);
    // G5: T2 += relu(H2+ba0) @ Wa
    gemm_sk<1, 512, 512, 64, 8, 2, 512>
        <<<dim3(8, 4, 2), 256, 0, stream>>>(H2, ba0, Wa, T2, NUL, NUL, NUL, NUL, NUL, NUL, nullptr, nullptr);
    // G6: H3 += RN @ Wa0 — pool-2 2-way softmax fused into loader, side-writes RN
    gemm_sk<10, 1024, 512, 64, 2, 5, 0>
        <<<dim3(16, 16, 2), 256, 0, stream>>>(NUL, NUL, Wa0, H3, T1, T2, IAB, P1, ba, bp, RN, nullptr);
    // G7: T3 += relu(H3+ba0) @ Wa
    gemm_sk<10, 512, 512, 64, 2, 2, 10 * 512>
        <<<dim3(8, 16, 2), 256, 0, stream>>>(H3, ba0, Wa, T3, NUL, NUL, NUL, NUL, NUL, NUL, nullptr, nullptr);
    // G8: HF += CAT @ Wl0 — pool-3 softmax + cat build fused into loader
    gemm_sk<1, 4096, 512, 128, 8, 6, 0>
        <<<dim3(32, 4, 2), 256, 0, stream>>>(NUL, NUL, Wl0, HF, T3, RN, P1, ba, bp, NUL, nullptr, nullptr);
    k_final<<<BO_, 512, 0, stream>>>(HF, bl0, Wl, bl, (float*)d_out);
}

// Round 5
// 164.860 us; speedup vs baseline: 7.4554x; 1.1491x over previous
//
#include <hip/hip_runtime.h>
#include <hip/hip_bf16.h>

#define B_    8
#define O_    4
#define L_    1024
#define E_    1024
#define BETA_ 512
#define NSEG_ 12
#define BO_   32
#define NCH_  16   // k1 row-chunks per bo (64 rows each)

// ---- workspace layout (float offsets). NO zero-init required anywhere.
enum : size_t {
  WS_SPART = 0,                                       // [32][16][12][1024] k1 chunk partials
  WS_X     = WS_SPART + (size_t)BO_ * NCH_ * 12 * E_, // [32][13][1024] segment means
  WS_P1P   = WS_X     + (size_t)BO_ * 13 * E_,        // [8][32][13][1024] X@Wp partials
  WS_H1P   = WS_P1P   + (size_t)8  * BO_ * 13 * E_,   // [16][32][10][512]
  WS_T1P   = WS_H1P   + (size_t)16 * BO_ * 10 * BETA_,// [8][32][10][512]
  WS_H2P   = WS_T1P   + (size_t)8  * BO_ * 10 * BETA_,// [8][32][512]
  WS_T2P   = WS_H2P   + (size_t)8  * BO_ * BETA_,     // [8][32][512]
  WS_H3P   = WS_T2P   + (size_t)8  * BO_ * BETA_,     // [16][32][10][512]
  WS_T3P   = WS_H3P   + (size_t)16 * BO_ * 10 * BETA_,// [8][32][10][512]
  WS_HFP   = WS_T3P   + (size_t)8  * BO_ * 10 * BETA_,// [32][32][512]
  WS_TE    = WS_HFP   + (size_t)32 * BO_ * BETA_,     // [32][13][1024] 1+relu(P1+bp)
  WS_T1B   = WS_TE    + (size_t)BO_ * 13 * E_,        // [32][10][512] T1+ba
  WS_IAB   = WS_T1B   + (size_t)BO_ * 10 * BETA_,     // [32][1024] ia|ib
  WS_RN    = WS_IAB   + (size_t)BO_ * 2 * BETA_,      // [32][10][1024] 1/na|1/nb
  WS_END   = WS_RN    + (size_t)BO_ * 10 * E_,
};

__device__ __forceinline__ float relu_(float v) { return v > 0.f ? v : 0.f; }

// ---------------- K1: per-chunk segment partial sums (plain stores, no atomics) -------
__global__ void k1_segsum(const float* __restrict__ hidden, const int* __restrict__ idx,
                          float* __restrict__ Spart) {
    const int chunk = blockIdx.x;  // 0..15, 64 rows each
    const int bo = blockIdx.y;
    const int b = bo >> 2;
    int cuts[13];
    cuts[0] = 1;
#pragma unroll
    for (int i = 0; i < 12; ++i) cuts[i + 1] = idx[b * NSEG_ + i];
    const int e4 = threadIdx.x << 2;
    float* sp = Spart + ((size_t)(bo * NCH_ + chunk) * 12) * E_ + e4;
    const float4 z = make_float4(0.f, 0.f, 0.f, 0.f);
#pragma unroll
    for (int m = 0; m < 12; ++m) *reinterpret_cast<float4*>(sp + (size_t)m * E_) = z;
    const int l0 = chunk * 64;
    const int l1 = l0 + 64;
    int lo = l0 < 1 ? 1 : l0;
    const int hi = l1 < cuts[12] ? l1 : cuts[12];
    if (lo >= hi) return;
    const float* base = hidden + (size_t)bo * (L_ * E_) + e4;
    int j = 0;
    while (j < 11 && cuts[j + 1] <= lo) ++j;
    int l = lo;
    while (l < hi) {
        const int e2 = (j < 11 && cuts[j + 1] < hi) ? cuts[j + 1] : hi;
        float sx = 0.f, sy = 0.f, sz = 0.f, sw = 0.f;
        for (; l < e2; ++l) {
            const float4 v = *reinterpret_cast<const float4*>(base + (size_t)l * E_);
            sx += v.x; sy += v.y; sz += v.z; sw += v.w;
        }
        float4 s; s.x = sx; s.y = sy; s.z = sz; s.w = sw;
        *reinterpret_cast<float4*>(sp + (size_t)j * E_) = s;  // block-owned slice
        ++j;
    }
}

// ---------------- K2: reduce chunk partials -> segment means X[32][13][1024] ----------
__global__ __launch_bounds__(256) void k2_means(
    const float* __restrict__ Spart, const int* __restrict__ idx,
    float* __restrict__ X) {
    const int bo = blockIdx.y;
    const int col = blockIdx.x * 256 + threadIdx.x;
    const int b = bo >> 2;
    int cuts[13];
    cuts[0] = 1;
#pragma unroll
    for (int i = 0; i < 12; ++i) cuts[i + 1] = idx[b * NSEG_ + i];
    const float* sp = Spart + (size_t)bo * NCH_ * 12 * E_ + col;
    float allc = 0.f;
#pragma unroll
    for (int m = 0; m < 12; ++m) {
        float s = 0.f;
#pragma unroll
        for (int ch = 0; ch < NCH_; ++ch) s += sp[((size_t)ch * 12 + m) * E_];
        X[((size_t)bo * 13 + m) * E_ + col] = s / (float)(cuts[m + 1] - cuts[m]);
        if (m < 10) allc += s;
    }
    X[((size_t)bo * 13 + 12) * E_ + col] = allc / (float)(cuts[10] - 1);
}

// ---------------- split-K GEMM, partial-slice output (no atomics) ---------------------
// OUTpart[((kidx*32+bo)*M + m)*N + c] = sum_{k in slice} xval(bo,m,k) * W[k*N+c]
// XF 0: xval = Xb[(bo*ML+m)*K+k]                       (plain, G1)
// XF 1: xval = 1+relu(sum_p Xb_part + xbias[k]); side-write TE          (G2)
// XF 2: xval = relu(sum_p Xb_part + xbias[k])                           (G3,G5,G7)
// XF 4: pool-1 softmax -> IAB; side-writes T1B(+ba) and IAB             (G4)
// XF 5: pool-2 2-way softmax -> RN; side-writes RN                      (G6)
// XF 6: pool-3 softmax + cat build                                      (G8)
template<int M, int ML, int K, int N, int KC, int BOG, int XF, int NPART>
__global__ __launch_bounds__(256) void gemm_sk(
    const float* __restrict__ Xb, const float* __restrict__ xbias,
    const float* __restrict__ W, float* __restrict__ OUT,
    const float* __restrict__ A0, const float* __restrict__ A1,
    const float* __restrict__ A2, const float* __restrict__ A3,
    float* __restrict__ SIDE, float* __restrict__ SIDE2) {
    const int kidx = blockIdx.x;
    const int k0 = kidx * KC;
    const int bo0 = blockIdx.y * BOG;
    const int c = blockIdx.z * 256 + threadIdx.x;
    const int tid = threadIdx.x;
    __shared__ __align__(16) float xs[BOG * ML * KC];

    for (int i = tid; i < BOG * ML * KC; i += 256) {
        const int kk = i % KC;
        const int rm = i / KC;
        const int m = rm % ML;
        const int bb = rm / ML;
        const int bo = bo0 + bb;
        const int k = k0 + kk;
        float v;
        if constexpr (XF == 0) {
            v = Xb[((size_t)bo * ML + m) * K + k];
        } else if constexpr (XF == 1) {
            float s = xbias[k];
#pragma unroll
            for (int p = 0; p < NPART; ++p)
                s += Xb[(((size_t)p * BO_ + bo) * ML + m) * K + k];
            v = 1.f + relu_(s);
            SIDE[((size_t)bo * ML + m) * K + k] = v;  // TE
        } else if constexpr (XF == 2) {
            float s = xbias[k];
#pragma unroll
            for (int p = 0; p < NPART; ++p)
                s += Xb[(((size_t)p * BO_ + bo) * ML + m) * K + k];
            v = relu_(s);
        } else if constexpr (XF == 4) {
            const int col = k & 511, half = k >> 9;
            const float bac = A2[col];
            float t[10], mx = -1e30f;
#pragma unroll
            for (int j = 0; j < 10; ++j) {
                float s = bac;
#pragma unroll
                for (int p = 0; p < NPART; ++p)
                    s += A0[(((size_t)p * BO_ + bo) * 10 + j) * BETA_ + col];
                t[j] = s;
                mx = fmaxf(mx, s);
            }
            if (half == 0) {
#pragma unroll
                for (int j = 0; j < 10; ++j)
                    SIDE2[((size_t)bo * 10 + j) * BETA_ + col] = t[j];  // T1B
            }
            float sw = 0.f, acc = 0.f;
#pragma unroll
            for (int j = 0; j < 10; ++j) {
                const float pj = expf(t[j] - mx);
                sw += pj;
                acc = fmaf(pj, A1[((size_t)bo * 13 + j) * E_ + half * BETA_ + col], acc);
            }
            v = acc / sw;
            SIDE[(size_t)bo * 1024 + k] = v;  // IAB
        } else if constexpr (XF == 5) {
            const int col = k & 511, half = k >> 9;
            const float tj = A0[((size_t)bo * 10 + m) * BETA_ + col];  // T1B (has +ba)
            float tI = A2[col];
#pragma unroll
            for (int p = 0; p < NPART; ++p)
                tI += A1[((size_t)p * BO_ + bo) * BETA_ + col];
            const float mx = fmaxf(tj, tI);
            const float e0 = expf(tj - mx);
            const float e1 = expf(tI - mx);
            const float ea = A3[((size_t)bo * 13 + m) * E_ + half * BETA_ + col];  // TE
            const float iv = SIDE2[(size_t)bo * 1024 + k];                         // IAB
            v = (e0 + e1) / (e0 * ea + e1 * iv);
            SIDE[((size_t)bo * 10 + m) * E_ + k] = v;  // RN
        } else {  // XF == 6
            if (k < 1024) {
                const int col = k & 511, half = k >> 9;
                const float bac = A2[col];
                float t[10], mx = -1e30f;
#pragma unroll
                for (int j = 0; j < 10; ++j) {
                    float s = bac;
#pragma unroll
                    for (int p = 0; p < NPART; ++p)
                        s += A0[(((size_t)p * BO_ + bo) * 10 + j) * BETA_ + col];
                    t[j] = s;
                    mx = fmaxf(mx, s);
                }
                float sw = 0.f, acc = 0.f;
#pragma unroll
                for (int j = 0; j < 10; ++j) {
                    const float pj = expf(t[j] - mx);
                    sw += pj;
                    acc = fmaf(pj, A1[((size_t)bo * 10 + j) * E_ + k], acc);  // RN
                }
                v = sw / acc;
            } else {
                const int region = k >> 10;
                const int row = (region == 1) ? 12 : (region == 2) ? 11 : 10;
                v = A3[((size_t)bo * 13 + row) * E_ + (k & 1023)];  // TE rows
            }
        }
        xs[i] = v;
    }
    __syncthreads();

    float acc[BOG][M];
#pragma unroll
    for (int b = 0; b < BOG; ++b)
#pragma unroll
        for (int m = 0; m < M; ++m) acc[b][m] = 0.f;
    const float* __restrict__ wp = W + (size_t)k0 * N + c;
    for (int k4 = 0; k4 < KC / 4; ++k4) {
        const float w0 = wp[(size_t)(4 * k4 + 0) * N];
        const float w1 = wp[(size_t)(4 * k4 + 1) * N];
        const float w2 = wp[(size_t)(4 * k4 + 2) * N];
        const float w3 = wp[(size_t)(4 * k4 + 3) * N];
#pragma unroll
        for (int b = 0; b < BOG; ++b) {
#pragma unroll
            for (int m = 0; m < M; ++m) {
                const float4 xv = *reinterpret_cast<const float4*>(&xs[(b * ML + m) * KC + 4 * k4]);
                float a = acc[b][m];
                a = fmaf(xv.x, w0, a);
                a = fmaf(xv.y, w1, a);
                a = fmaf(xv.z, w2, a);
                a = fmaf(xv.w, w3, a);
                acc[b][m] = a;
            }
        }
    }
#pragma unroll
    for (int b = 0; b < BOG; ++b) {
        float* op = OUT + (((size_t)kidx * BO_ + bo0 + b) * M) * N + c;
#pragma unroll
        for (int m = 0; m < M; ++m) op[(size_t)m * N] = acc[b][m];  // plain store
    }
}

// ---------------- final: out[bo] = relu(sum_p HFpart + bl0) . Wl + bl -----------------
__global__ void __launch_bounds__(512) k_final(
    const float* __restrict__ HFP, const float* __restrict__ bl0,
    const float* __restrict__ Wl, const float* __restrict__ bl,
    float* __restrict__ out) {
    const int bo = blockIdx.x;
    const int c = threadIdx.x;
    float s = bl0[c];
#pragma unroll
    for (int p = 0; p < 32; ++p) s += HFP[((size_t)p * BO_ + bo) * BETA_ + c];
    float partial = relu_(s) * Wl[c];
#pragma unroll
    for (int off = 32; off > 0; off >>= 1) partial += __shfl_down(partial, off, 64);
    __shared__ float red[8];
    if ((c & 63) == 0) red[c >> 6] = partial;
    __syncthreads();
    if (c == 0) out[bo] = red[0] + red[1] + red[2] + red[3] + red[4] + red[5] + red[6] + red[7] + bl[0];
}

extern "C" void kernel_launch(void* const* d_in, const int* in_sizes, int n_in,
                              void* d_out, int out_size, void* d_ws, size_t ws_size,
                              hipStream_t stream) {
    const float* hidden = (const float*)d_in[0];
    const int* idx = (const int*)d_in[1];
    const float* Wp  = (const float*)d_in[2];
    const float* bp  = (const float*)d_in[3];
    const float* Wa0 = (const float*)d_in[4];
    const float* ba0 = (const float*)d_in[5];
    const float* Wa  = (const float*)d_in[6];
    const float* ba  = (const float*)d_in[7];
    const float* Wl0 = (const float*)d_in[8];
    const float* bl0 = (const float*)d_in[9];
    const float* Wl  = (const float*)d_in[10];
    const float* bl  = (const float*)d_in[11];
    float* ws = (float*)d_ws;
    float* SPART = ws + WS_SPART;
    float* X     = ws + WS_X;
    float* P1P   = ws + WS_P1P;
    float* H1P   = ws + WS_H1P;
    float* T1P   = ws + WS_T1P;
    float* H2P   = ws + WS_H2P;
    float* T2P   = ws + WS_T2P;
    float* H3P   = ws + WS_H3P;
    float* T3P   = ws + WS_T3P;
    float* HFP   = ws + WS_HFP;
    float* TE    = ws + WS_TE;
    float* T1B   = ws + WS_T1B;
    float* IAB   = ws + WS_IAB;
    float* RN    = ws + WS_RN;
    const float* NUL = nullptr;

    k1_segsum<<<dim3(NCH_, BO_), 256, 0, stream>>>(hidden, idx, SPART);
    k2_means<<<dim3(4, BO_), 256, 0, stream>>>(SPART, idx, X);
    // G1: P1part = X @ Wp  (M=13,K=1024,N=1024, kidx=8)
    gemm_sk<13, 13, 1024, 1024, 128, 2, 0, 1>
        <<<dim3(8, 16, 4), 256, 0, stream>>>(X, NUL, Wp, P1P, NUL, NUL, NUL, NUL, nullptr, nullptr);
    // G2: H1part = TE(rows<10) @ Wa0 ; side-writes TE  (kidx=16; sums 8 P1 partials)
    gemm_sk<10, 13, 1024, 512, 64, 2, 1, 8>
        <<<dim3(16, 16, 2), 256, 0, stream>>>(P1P, bp, Wa0, H1P, NUL, NUL, NUL, NUL, TE, nullptr);
    // G3: T1part = relu(sum H1part + ba0) @ Wa  (kidx=8; sums 16)
    gemm_sk<10, 10, 512, 512, 64, 2, 2, 16>
        <<<dim3(8, 16, 2), 256, 0, stream>>>(H1P, ba0, Wa, T1P, NUL, NUL, NUL, NUL, nullptr, nullptr);
    // G4: H2part = IAB @ Wa0 ; pool-1 softmax in loader; side-writes T1B, IAB
    gemm_sk<1, 1, 1024, 512, 128, 8, 4, 8>
        <<<dim3(8, 4, 2), 256, 0, stream>>>(NUL, NUL, Wa0, H2P, T1P, TE, ba, NUL, IAB, T1B);
    // G5: T2part = relu(sum H2part + ba0) @ Wa
    gemm_sk<1, 1, 512, 512, 64, 8, 2, 8>
        <<<dim3(8, 4, 2), 256, 0, stream>>>(H2P, ba0, Wa, T2P, NUL, NUL, NUL, NUL, nullptr, nullptr);
    // G6: H3part = RN @ Wa0 ; pool-2 2-way softmax in loader; side-writes RN
    gemm_sk<10, 10, 1024, 512, 64, 2, 5, 8>
        <<<dim3(16, 16, 2), 256, 0, stream>>>(NUL, NUL, Wa0, H3P, T1B, T2P, ba, TE, RN, IAB);
    // G7: T3part = relu(sum H3part + ba0) @ Wa  (sums 16)
    gemm_sk<10, 10, 512, 512, 64, 2, 2, 16>
        <<<dim3(8, 16, 2), 256, 0, stream>>>(H3P, ba0, Wa, T3P, NUL, NUL, NUL, NUL, nullptr, nullptr);
    // G8: HFpart = CAT @ Wl0 ; pool-3 softmax + cat build in loader (kidx=32)
    gemm_sk<1, 1, 4096, 512, 128, 8, 6, 8>
        <<<dim3(32, 4, 2), 256, 0, stream>>>(NUL, NUL, Wl0, HFP, T3P, RN, ba, TE, nullptr, nullptr);
    k_final<<<BO_, 512, 0, stream>>>(HFP, bl0, Wl, bl, (float*)d_out);
}